// Round 4
// baseline (187.802 us; speedup 1.0000x reference)
//
#include <hip/hip_runtime.h>
#include <math.h>

// Max-pool over gathered neighbor features, with per-point index SORTING to
// create a machine-wide coordinated sweep over the feature array.
//
//   features: (N, F=128) f32, neighbor_indices: (NP, K=32) i32
//   out: (NP, F=128) f32 = max over K of features[idx[p][k]][:]
//
// Key idea: sorted neighbor lists mean loop step k accesses rows near the
// k/32 quantile of [0,N) for EVERY group simultaneously -> the instantaneous
// working set is ~4 MB (order-statistic spread), L2-resident per XCD,
// instead of 51.2 MB of uniform random gathers. Max is commutative so
// reordering is exact.
//
// Block = 256 threads = 32 points. Phases:
//   1. cooperative load of the block's 32x32 indices into LDS
//   2. 32-lane bitonic sort per point (8 sub-sorters x 4 rounds)
//   3. gather: 8 lanes/point, lane l owns float4 lanes {l, l+8, l+16, l+24};
//      per neighbor the group reads one full 512 B row (coalesced).

__global__ __launch_bounds__(256) void pool_max_sorted(
    const float4* __restrict__ feat4,   // (N, 32) rows of float4
    const int*    __restrict__ nbr,     // (NP, 32)
    float4*       __restrict__ out4,    // (NP, 32)
    int NP)
{
    __shared__ alignas(16) int lds_idx[32 * 32];   // 32 points x 32 indices

    const int t = threadIdx.x;

    // ---- phase 1: load indices (coalesced int4) ----
    {
        size_t gbase = (size_t)blockIdx.x * 1024 + (size_t)t * 4;
        int4 v = make_int4(0, 0, 0, 0);
        if (gbase < (size_t)NP * 32)
            v = *(const int4*)(nbr + gbase);
        *(int4*)&lds_idx[t * 4] = v;
    }
    __syncthreads();

    // ---- phase 2: bitonic sort 32 indices per point ----
    // 8 sub-sorters (32 lanes each); each sorts 4 points sequentially.
    {
        const int lane31 = t & 31;
        const int s = t >> 5;                       // sub-sorter 0..7
        for (int r = 0; r < 4; ++r) {
            const int pl = s + r * 8;               // point slot 0..31
            int v = lds_idx[pl * 32 + lane31];
            #pragma unroll
            for (int k = 2; k <= 32; k <<= 1) {
                #pragma unroll
                for (int j = k >> 1; j > 0; j >>= 1) {
                    int o = __shfl_xor(v, j, 32);
                    bool lower = (lane31 & j) == 0;
                    bool up    = (lane31 & k) == 0;
                    int mn = v < o ? v : o;
                    int mx = v < o ? o : v;
                    v = (lower == up) ? mn : mx;
                }
            }
            lds_idx[pl * 32 + lane31] = v;
        }
    }
    __syncthreads();

    // ---- phase 3: gather + max, ascending row order ----
    const int g = t >> 3;                           // point slot 0..31
    const int l = t & 7;                            // lane within group
    const int p = blockIdx.x * 32 + g;
    if (p >= NP) return;

    const int4* sj = (const int4*)&lds_idx[g * 32];
    float4 m0 = make_float4(-INFINITY, -INFINITY, -INFINITY, -INFINITY);
    float4 m1 = m0, m2 = m0, m3 = m0;

    #pragma unroll
    for (int kb = 0; kb < 8; ++kb) {
        int4 jj = sj[kb];                           // 4 sorted indices (LDS broadcast)
        {
            const float4* b = feat4 + (size_t)jj.x * 32 + l;
            float4 v0 = b[0], v1 = b[8], v2 = b[16], v3 = b[24];
            m0.x = fmaxf(m0.x, v0.x); m0.y = fmaxf(m0.y, v0.y); m0.z = fmaxf(m0.z, v0.z); m0.w = fmaxf(m0.w, v0.w);
            m1.x = fmaxf(m1.x, v1.x); m1.y = fmaxf(m1.y, v1.y); m1.z = fmaxf(m1.z, v1.z); m1.w = fmaxf(m1.w, v1.w);
            m2.x = fmaxf(m2.x, v2.x); m2.y = fmaxf(m2.y, v2.y); m2.z = fmaxf(m2.z, v2.z); m2.w = fmaxf(m2.w, v2.w);
            m3.x = fmaxf(m3.x, v3.x); m3.y = fmaxf(m3.y, v3.y); m3.z = fmaxf(m3.z, v3.z); m3.w = fmaxf(m3.w, v3.w);
        }
        {
            const float4* b = feat4 + (size_t)jj.y * 32 + l;
            float4 v0 = b[0], v1 = b[8], v2 = b[16], v3 = b[24];
            m0.x = fmaxf(m0.x, v0.x); m0.y = fmaxf(m0.y, v0.y); m0.z = fmaxf(m0.z, v0.z); m0.w = fmaxf(m0.w, v0.w);
            m1.x = fmaxf(m1.x, v1.x); m1.y = fmaxf(m1.y, v1.y); m1.z = fmaxf(m1.z, v1.z); m1.w = fmaxf(m1.w, v1.w);
            m2.x = fmaxf(m2.x, v2.x); m2.y = fmaxf(m2.y, v2.y); m2.z = fmaxf(m2.z, v2.z); m2.w = fmaxf(m2.w, v2.w);
            m3.x = fmaxf(m3.x, v3.x); m3.y = fmaxf(m3.y, v3.y); m3.z = fmaxf(m3.z, v3.z); m3.w = fmaxf(m3.w, v3.w);
        }
        {
            const float4* b = feat4 + (size_t)jj.z * 32 + l;
            float4 v0 = b[0], v1 = b[8], v2 = b[16], v3 = b[24];
            m0.x = fmaxf(m0.x, v0.x); m0.y = fmaxf(m0.y, v0.y); m0.z = fmaxf(m0.z, v0.z); m0.w = fmaxf(m0.w, v0.w);
            m1.x = fmaxf(m1.x, v1.x); m1.y = fmaxf(m1.y, v1.y); m1.z = fmaxf(m1.z, v1.z); m1.w = fmaxf(m1.w, v1.w);
            m2.x = fmaxf(m2.x, v2.x); m2.y = fmaxf(m2.y, v2.y); m2.z = fmaxf(m2.z, v2.z); m2.w = fmaxf(m2.w, v2.w);
            m3.x = fmaxf(m3.x, v3.x); m3.y = fmaxf(m3.y, v3.y); m3.z = fmaxf(m3.z, v3.z); m3.w = fmaxf(m3.w, v3.w);
        }
        {
            const float4* b = feat4 + (size_t)jj.w * 32 + l;
            float4 v0 = b[0], v1 = b[8], v2 = b[16], v3 = b[24];
            m0.x = fmaxf(m0.x, v0.x); m0.y = fmaxf(m0.y, v0.y); m0.z = fmaxf(m0.z, v0.z); m0.w = fmaxf(m0.w, v0.w);
            m1.x = fmaxf(m1.x, v1.x); m1.y = fmaxf(m1.y, v1.y); m1.z = fmaxf(m1.z, v1.z); m1.w = fmaxf(m1.w, v1.w);
            m2.x = fmaxf(m2.x, v2.x); m2.y = fmaxf(m2.y, v2.y); m2.z = fmaxf(m2.z, v2.z); m2.w = fmaxf(m2.w, v2.w);
            m3.x = fmaxf(m3.x, v3.x); m3.y = fmaxf(m3.y, v3.y); m3.z = fmaxf(m3.z, v3.z); m3.w = fmaxf(m3.w, v3.w);
        }
    }

    float4* ob = out4 + (size_t)p * 32 + l;
    ob[0]  = m0;
    ob[8]  = m1;
    ob[16] = m2;
    ob[24] = m3;
}

extern "C" void kernel_launch(void* const* d_in, const int* in_sizes, int n_in,
                              void* d_out, int out_size, void* d_ws, size_t ws_size,
                              hipStream_t stream) {
    // inputs: [0] points (N,3) f32 (unused), [1] features (N,128) f32,
    //         [2] neighbor_indices (NP,32) i32
    const float* features = (const float*)d_in[1];
    const int*   nbr      = (const int*)d_in[2];
    float*       out      = (float*)d_out;

    const int F = 128;
    int NP = out_size / F;                 // 50000

    const int threads = 256;               // 32 points per block
    int grid = (NP + 31) / 32;             // 1563 blocks
    pool_max_sorted<<<grid, threads, 0, stream>>>(
        (const float4*)features, nbr, (float4*)out, NP);
}

// Round 7
// 186.643 us; speedup vs baseline: 1.0062x; 1.0062x over previous
//
#include <hip/hip_runtime.h>
#include <math.h>

// Max-pool over gathered neighbor features: per-point sorted walk + VALUE-
// WINDOW PACING. 16 mega-steps with a block barrier between; step s only
// consumes indices < (s+1)*N/16, so the whole machine sweeps the feature
// array in hard 3.2 MB windows (smaller than the 4.4 MB order-statistic
// spread that thrashed the 4 MB/XCD L2 in the unpaced sorted version).
// Goal: machine-wide temporal clustering of row re-touches so L2/L3 serve
// them instead of the HBM random-access path.
//
// Dual-entry inner body: max is idempotent, so an odd tail re-processes the
// same row twice (the duplicate load is an L1 hit) — keeps 8 independent
// loads in flight per wave with zero divergence cost.

__global__ __launch_bounds__(256) void pool_max_paced(
    const float4* __restrict__ feat4,   // (N, 32) rows of float4
    const int*    __restrict__ nbr,     // (NP, 32)
    float4*       __restrict__ out4,    // (NP, 32)
    int NP, int Nrows)
{
    __shared__ alignas(16) int lds_idx[32 * 32];   // 32 points x 32 indices
    const int t = threadIdx.x;

    // ---- phase 1: load indices (coalesced int4) ----
    {
        size_t gbase = (size_t)blockIdx.x * 1024 + (size_t)t * 4;
        int4 v = make_int4(0, 0, 0, 0);
        if (gbase < (size_t)NP * 32)
            v = *(const int4*)(nbr + gbase);
        *(int4*)&lds_idx[t * 4] = v;
    }
    __syncthreads();

    // ---- phase 2: bitonic sort 32 indices per point ----
    {
        const int lane31 = t & 31;
        const int s = t >> 5;                       // sub-sorter 0..7
        for (int r = 0; r < 4; ++r) {
            const int pl = s + r * 8;               // point slot 0..31
            int v = lds_idx[pl * 32 + lane31];
            #pragma unroll
            for (int k = 2; k <= 32; k <<= 1) {
                #pragma unroll
                for (int j = k >> 1; j > 0; j >>= 1) {
                    int o = __shfl_xor(v, j, 32);
                    bool lower = (lane31 & j) == 0;
                    bool up    = (lane31 & k) == 0;
                    int mn = v < o ? v : o;
                    int mx = v < o ? o : v;
                    v = (lower == up) ? mn : mx;
                }
            }
            lds_idx[pl * 32 + lane31] = v;
        }
    }
    __syncthreads();

    // ---- phase 3: paced gather + max ----
    const int g = t >> 3;                           // point slot 0..31
    const int l = t & 7;                            // lane within group
    const int p = blockIdx.x * 32 + g;
    const bool active = (p < NP);
    const int* sj = &lds_idx[g * 32];

    float4 m0 = make_float4(-INFINITY, -INFINITY, -INFINITY, -INFINITY);
    float4 m1 = m0, m2 = m0, m3 = m0;
    int ptr = 0;

    #pragma unroll 1
    for (int s = 0; s < 16; ++s) {
        int thresh = (int)(((long long)(s + 1) * (long long)Nrows) >> 4);
        if (active) {
            while (ptr < 32 && sj[ptr] < thresh) {
                int j0 = sj[ptr];
                bool two = (ptr + 1 < 32) && (sj[ptr + 1] < thresh);
                int j1 = two ? sj[ptr + 1] : j0;    // duplicate row if odd tail
                ptr += two ? 2 : 1;

                const float4* a = feat4 + (size_t)j0 * 32 + l;
                const float4* b = feat4 + (size_t)j1 * 32 + l;
                float4 a0 = a[0], a1 = a[8], a2 = a[16], a3 = a[24];
                float4 b0 = b[0], b1 = b[8], b2 = b[16], b3 = b[24];
                m0.x = fmaxf(m0.x, fmaxf(a0.x, b0.x));
                m0.y = fmaxf(m0.y, fmaxf(a0.y, b0.y));
                m0.z = fmaxf(m0.z, fmaxf(a0.z, b0.z));
                m0.w = fmaxf(m0.w, fmaxf(a0.w, b0.w));
                m1.x = fmaxf(m1.x, fmaxf(a1.x, b1.x));
                m1.y = fmaxf(m1.y, fmaxf(a1.y, b1.y));
                m1.z = fmaxf(m1.z, fmaxf(a1.z, b1.z));
                m1.w = fmaxf(m1.w, fmaxf(a1.w, b1.w));
                m2.x = fmaxf(m2.x, fmaxf(a2.x, b2.x));
                m2.y = fmaxf(m2.y, fmaxf(a2.y, b2.y));
                m2.z = fmaxf(m2.z, fmaxf(a2.z, b2.z));
                m2.w = fmaxf(m2.w, fmaxf(a2.w, b2.w));
                m3.x = fmaxf(m3.x, fmaxf(a3.x, b3.x));
                m3.y = fmaxf(m3.y, fmaxf(a3.y, b3.y));
                m3.z = fmaxf(m3.z, fmaxf(a3.z, b3.z));
                m3.w = fmaxf(m3.w, fmaxf(a3.w, b3.w));
            }
        }
        __syncthreads();   // all threads reach this (guard is on the body only)
    }

    if (active) {
        float4* ob = out4 + (size_t)p * 32 + l;
        ob[0]  = m0;
        ob[8]  = m1;
        ob[16] = m2;
        ob[24] = m3;
    }
}

extern "C" void kernel_launch(void* const* d_in, const int* in_sizes, int n_in,
                              void* d_out, int out_size, void* d_ws, size_t ws_size,
                              hipStream_t stream) {
    // inputs: [0] points (N,3) f32 (unused), [1] features (N,128) f32,
    //         [2] neighbor_indices (NP,32) i32
    const float* features = (const float*)d_in[1];
    const int*   nbr      = (const int*)d_in[2];
    float*       out      = (float*)d_out;

    const int F = 128;
    int NP    = out_size / F;              // 50000
    int Nrows = in_sizes[1] / F;           // 100000

    const int threads = 256;               // 32 points per block
    int grid = (NP + 31) / 32;             // 1563 blocks
    pool_max_paced<<<grid, threads, 0, stream>>>(
        (const float4*)features, nbr, (float4*)out, NP, Nrows);
}